// Round 10
// baseline (46.456 us; speedup 1.0000x reference)
//
#include <hip/hip_runtime.h>
#include <hip/hip_bf16.h>

// DenSparse: out[b, dst_e] += w_e * x[b, src_e]
// B=32, IN=OUT=65536, NNZ=1048576
//
// Round 10 (revert r9 coop-launch failure; improve proven r8 3-node pipeline):
//  - prep512: 512 UNIFORM blocks, each = 128-col bf16 transpose slab + 2048
//    edges of rank-capture partition (r8 had only 128 partition blocks =
//    0.5/CU parallelism during the partition phase; now 2/CU).
//  - accum: runs padded to 16 -> each lane issues 4 independent gathers per
//    iteration (ILP 2->4), ~40% fewer latency rounds for +20% padded work.

#define IN_SIZE  65536
#define OUT_SIZE 65536
#define BATCH    32
#define NBKT     512      // buckets (dst >> 7)
#define CAP      2560     // per-bucket region capacity (mean 2048, 11 sigma)
#define COLS_PB  128      // transpose columns per prep block
#define EDGES_PB 2048     // edges per prep block (2 per thread)
#define PADCAP   4480     // >= CAP + 128*15 (pad-16)

typedef unsigned int uint;
typedef unsigned short ushort;

__device__ __forceinline__ float bf2f(ushort v) {
    return __uint_as_float((uint)v << 16);
}

// ---------------- prep: transpose slab + partition slice, one block each ----------------
__global__ __launch_bounds__(1024) void prep512(
        const float* __restrict__ x, ushort* __restrict__ xt,
        const int* __restrict__ dst, const int* __restrict__ src,
        const float* __restrict__ w, int* __restrict__ gcnt,
        uint2* __restrict__ rec, int nnz) {
    __shared__ float tile[32][132];
    __shared__ int cnt[NBKT];
    __shared__ int base[NBKT];
    const int tid = threadIdx.x;
    const int bid = blockIdx.x;

    // issue edge loads first (latency hides under transpose work)
    uint m[2]; float wv[2]; bool val[2]; int rk[2];
    {
        const int e0 = bid * EDGES_PB + tid * 2;
        if (e0 + 2 <= nnz) {
            int2   d2 = *(const int2*)(dst + e0);
            int2   s2 = *(const int2*)(src + e0);
            float2 w2 = *(const float2*)(w + e0);
            m[0] = (uint)(s2.x & 0xFFFF) | ((uint)d2.x << 16); wv[0] = w2.x; val[0] = true;
            m[1] = (uint)(s2.y & 0xFFFF) | ((uint)d2.y << 16); wv[1] = w2.y; val[1] = true;
        } else {
            #pragma unroll
            for (int u = 0; u < 2; ++u) {
                int e = e0 + u;
                val[u] = (e < nnz);
                m[u]  = val[u] ? ((uint)(src[e] & 0xFFFF) | ((uint)dst[e] << 16)) : 0u;
                wv[u] = val[u] ? w[e] : 0.f;
            }
        }
    }
    // transpose loads + LDS
    {
        const int i0 = bid * COLS_PB;
        int ty = tid >> 5, tx = tid & 31;
        float4 vv = *(const float4*)(x + (size_t)ty * IN_SIZE + i0 + tx * 4);
        *(float4*)&tile[ty][tx * 4] = vv;
    }
    if (tid < NBKT) cnt[tid] = 0;
    __syncthreads();
    // transpose store (bf16, coalesced ushort4)
    {
        const int i0 = bid * COLS_PB;
        int c = tid >> 3, sub = tid & 7;
        ushort4 o;
        __hip_bfloat16 h0 = __float2bfloat16(tile[sub * 4 + 0][c]);
        __hip_bfloat16 h1 = __float2bfloat16(tile[sub * 4 + 1][c]);
        __hip_bfloat16 h2 = __float2bfloat16(tile[sub * 4 + 2][c]);
        __hip_bfloat16 h3 = __float2bfloat16(tile[sub * 4 + 3][c]);
        o.x = *(ushort*)&h0; o.y = *(ushort*)&h1;
        o.z = *(ushort*)&h2; o.w = *(ushort*)&h3;
        *(ushort4*)(xt + ((size_t)(i0 + c)) * BATCH + sub * 4) = o;
    }
    // partition: count w/ rank capture -> reserve -> dense scatter
    #pragma unroll
    for (int u = 0; u < 2; ++u)
        if (val[u]) rk[u] = atomicAdd(&cnt[m[u] >> 23], 1);
    __syncthreads();
    if (tid < NBKT) base[tid] = atomicAdd(&gcnt[tid], cnt[tid]);
    __syncthreads();
    #pragma unroll
    for (int u = 0; u < 2; ++u) {
        if (val[u]) {
            uint q = m[u] >> 23;
            int pos = base[q] + rk[u];
            if (pos < CAP) {   // statistically unreachable overflow guard
                rec[(size_t)q * CAP + pos] = make_uint2(m[u], __float_as_uint(wv[u]));
            }
        }
    }
}

// ---------------- per-bucket: rank-sort (16-padded) + wave-uniform accumulate ----------------
__global__ __launch_bounds__(1024) void accum_wave(
        const ushort* __restrict__ xt,
        const uint2*  __restrict__ rec,
        const int*    __restrict__ gcnt,
        float* __restrict__ out) {
    __shared__ uint2 bufB[PADCAP];   // sorted+padded records; reused as out-stage
    __shared__ int   soff[129];      // padded CSR offsets
    __shared__ int   scnt[128];      // counts (rank source)
    __shared__ int   sS[128];        // scan workspace

    const int q   = blockIdx.x;
    const int tid = threadIdx.x;
    const int n   = min(gcnt[q], CAP);
    const size_t beg = (size_t)q * CAP;

    if (tid < 128) scnt[tid] = 0;
    __syncthreads();

    // load records (<=3 per thread, static) + rank capture
    uint2 rr[3]; int rk[3]; bool v[3];
    #pragma unroll
    for (int u = 0; u < 3; ++u) {
        int j = tid + (u << 10);
        v[u] = (j < n);
        if (v[u]) {
            rr[u] = rec[beg + j];
            rk[u] = atomicAdd(&scnt[(rr[u].x >> 16) & 127u], 1);
        }
    }
    __syncthreads();

    // exclusive scan of PADDED counts (ceil(c/16)*16)
    int own = 0;
    if (tid < 128) { own = (scnt[tid] + 15) & ~15; sS[tid] = own; }
    __syncthreads();
    #pragma unroll
    for (int ofs = 1; ofs < 128; ofs <<= 1) {
        int t = 0;
        if (tid < 128 && tid >= ofs) t = sS[tid - ofs];
        __syncthreads();
        if (tid < 128) sS[tid] += t;
        __syncthreads();
    }
    if (tid < 128) {
        soff[tid] = sS[tid] - own;
        if (tid == 127) soff[128] = sS[127];
    }
    __syncthreads();

    // zero padded region, then scatter real records (pads stay w=0)
    const int pn = soff[128];
    for (int j = tid; j < pn; j += 1024) bufB[j] = make_uint2(0u, 0u);
    __syncthreads();
    #pragma unroll
    for (int u = 0; u < 3; ++u) {
        if (v[u]) {
            int d = (rr[u].x >> 16) & 127;
            bufB[soff[d] + rk[u]] = rr[u];
        }
    }
    __syncthreads();

    // wave-uniform accumulate: wave wvid owns 8 dsts sequentially; lane =
    // eslot (0..3) x batch-pair k2. Runs are multiples of 16 -> each lane
    // issues 4 independent gathers per iteration, identical trips wave-wide.
    const int wvid  = tid >> 6;
    const int eslot = (tid >> 4) & 3;
    const int k2    = (tid & 15) << 1;
    float2 a[8];
    #pragma unroll
    for (int dd = 0; dd < 8; ++dd) a[dd] = make_float2(0.f, 0.f);
    #pragma unroll
    for (int dd = 0; dd < 8; ++dd) {
        const int d = (wvid << 3) + dd;
        int i = soff[d] + eslot;
        const int e2 = soff[d + 1];
        for (; i < e2; i += 16) {
            uint2 r0 = bufB[i];
            uint2 r1 = bufB[i + 4];
            uint2 r2 = bufB[i + 8];
            uint2 r3 = bufB[i + 12];
            uint p0 = *(const uint*)(xt + (r0.x & 0xFFFFu) * BATCH + k2);
            uint p1 = *(const uint*)(xt + (r1.x & 0xFFFFu) * BATCH + k2);
            uint p2 = *(const uint*)(xt + (r2.x & 0xFFFFu) * BATCH + k2);
            uint p3 = *(const uint*)(xt + (r3.x & 0xFFFFu) * BATCH + k2);
            float w0 = __uint_as_float(r0.y), w1 = __uint_as_float(r1.y);
            float w2 = __uint_as_float(r2.y), w3 = __uint_as_float(r3.y);
            a[dd].x += w0 * bf2f((ushort)(p0 & 0xFFFFu));
            a[dd].y += w0 * bf2f((ushort)(p0 >> 16));
            a[dd].x += w1 * bf2f((ushort)(p1 & 0xFFFFu));
            a[dd].y += w1 * bf2f((ushort)(p1 >> 16));
            a[dd].x += w2 * bf2f((ushort)(p2 & 0xFFFFu));
            a[dd].y += w2 * bf2f((ushort)(p2 >> 16));
            a[dd].x += w3 * bf2f((ushort)(p3 & 0xFFFFu));
            a[dd].y += w3 * bf2f((ushort)(p3 >> 16));
        }
    }
    // combine the 4 edge-slots (lanes differing in bits 4,5)
    #pragma unroll
    for (int dd = 0; dd < 8; ++dd) {
        a[dd].x += __shfl_xor(a[dd].x, 16);
        a[dd].x += __shfl_xor(a[dd].x, 32);
        a[dd].y += __shfl_xor(a[dd].y, 16);
        a[dd].y += __shfl_xor(a[dd].y, 32);
    }
    __syncthreads();   // bufB dead
    // stage (reuse bufB as float stg[128][34]) + coalesced slab write
    float* stg = (float*)bufB;
    if (eslot == 0) {
        #pragma unroll
        for (int dd = 0; dd < 8; ++dd)
            *(float2*)&stg[((wvid << 3) + dd) * 34 + k2] = a[dd];
    }
    __syncthreads();
    #pragma unroll
    for (int kk = 0; kk < 4; ++kk) {
        int idx = tid + (kk << 10);
        int row = idx >> 7;    // 0..31
        int col = idx & 127;
        out[(size_t)row * OUT_SIZE + (q << 7) + col] = stg[col * 34 + row];
    }
}

// ---------------- fallback ----------------
__global__ void zero_f4(float4* __restrict__ p, int n4) {
    int i = blockIdx.x * blockDim.x + threadIdx.x;
    if (i < n4) p[i] = make_float4(0.f, 0.f, 0.f, 0.f);
}
__global__ void scatter_direct(const float* __restrict__ x,
                               const float* __restrict__ w,
                               const int*   __restrict__ dst,
                               const int*   __restrict__ src,
                               float*       __restrict__ out,
                               int nnz) {
    int t = blockIdx.x * blockDim.x + threadIdx.x;
    int e = t >> 5;
    int b = t & 31;
    if (e < nnz) {
        atomicAdd(&out[(size_t)b * OUT_SIZE + dst[e]],
                  w[e] * x[(size_t)b * IN_SIZE + src[e]]);
    }
}

extern "C" void kernel_launch(void* const* d_in, const int* in_sizes, int n_in,
                              void* d_out, int out_size, void* d_ws, size_t ws_size,
                              hipStream_t stream) {
    const float* x   = (const float*)d_in[0];   // [32][65536]
    const float* w   = (const float*)d_in[1];   // [NNZ]
    const int*   dst = (const int*)d_in[2];     // [NNZ]
    const int*   src = (const int*)d_in[3];     // [NNZ]
    float*       out = (float*)d_out;           // [32][65536]
    const int nnz = in_sizes[1];

    // workspace layout (14 MiB + 2KB)
    const size_t XT_OFF   = 0;                                   // bf16 xt: 4 MiB
    const size_t REC_OFF  = (size_t)4 << 20;                     // uint2: 10 MiB
    const size_t GCNT_OFF = REC_OFF + (size_t)NBKT * CAP * 8;    // 2 KB
    const size_t WS_NEEDED = GCNT_OFF + NBKT * 4;

    if (ws_size >= WS_NEEDED && nnz <= NBKT * EDGES_PB) {
        ushort* xt   = (ushort*)((char*)d_ws + XT_OFF);
        uint2*  rec  = (uint2*) ((char*)d_ws + REC_OFF);
        int*    gcnt = (int*)   ((char*)d_ws + GCNT_OFF);

        hipMemsetAsync(gcnt, 0, NBKT * sizeof(int), stream);
        prep512<<<NBKT, 1024, 0, stream>>>(x, xt, dst, src, w, gcnt, rec, nnz);
        accum_wave<<<NBKT, 1024, 0, stream>>>(xt, rec, gcnt, out);
    } else {
        int n4 = out_size / 4;
        zero_f4<<<(n4 + 255) / 256, 256, 0, stream>>>((float4*)d_out, n4);
        long long total = (long long)nnz * 32;
        int blocks = (int)((total + 255) / 256);
        scatter_direct<<<blocks, 256, 0, stream>>>(x, w, dst, src, out, nnz);
    }
}